// Round 2
// baseline (555.331 us; speedup 1.0000x reference)
//
#include <hip/hip_runtime.h>

#define CS   1024
#define CZ   128

typedef __attribute__((ext_vector_type(8))) short short8;
typedef __attribute__((ext_vector_type(4))) float floatx4;

static __device__ __forceinline__ unsigned short f2bf(float f) {
  unsigned int u = __float_as_uint(f);
  u = (u + 0x7fffu + ((u >> 16) & 1u)) >> 16;   // round-to-nearest-even
  return (unsigned short)u;
}

// ---------------- Kernel 1: LayerNorm + proj -> q (bf16), k (f32) ----------------
__global__ __launch_bounds__(256) void prep_kernel(
    const float* __restrict__ seq,
    const float* __restrict__ lnw,
    const float* __restrict__ lnb,
    const float* __restrict__ pw,
    const float* __restrict__ pb,
    unsigned short* __restrict__ q_ws,
    float* __restrict__ k_ws) {
  const int row  = blockIdx.x;
  const int tid  = threadIdx.x;
  const int lane = tid & 63;
  const int wave = tid >> 6;

  __shared__ __align__(16) float snf[CS];
  __shared__ float sred[8];
  __shared__ float pacc[4][64];

  // each thread owns 4 consecutive elements
  float4 v = *(const float4*)(seq + (size_t)row * CS + tid * 4);
  float s  = v.x + v.y + v.z + v.w;
  float ss = v.x * v.x + v.y * v.y + v.z * v.z + v.w * v.w;
  #pragma unroll
  for (int off = 32; off >= 1; off >>= 1) {
    s  += __shfl_down(s, off, 64);
    ss += __shfl_down(ss, off, 64);
  }
  if (lane == 0) { sred[wave] = s; sred[4 + wave] = ss; }
  __syncthreads();
  const float mu   = (sred[0] + sred[1] + sred[2] + sred[3]) * (1.0f / CS);
  const float var  = (sred[4] + sred[5] + sred[6] + sred[7]) * (1.0f / CS) - mu * mu;
  const float rstd = rsqrtf(var + 1e-5f);
  {
    const int c = tid * 4;
    float4 gw = *(const float4*)(lnw + c);
    float4 gb = *(const float4*)(lnb + c);
    snf[c + 0] = (v.x - mu) * rstd * gw.x + gb.x;
    snf[c + 1] = (v.y - mu) * rstd * gw.y + gb.y;
    snf[c + 2] = (v.z - mu) * rstd * gw.z + gb.z;
    snf[c + 3] = (v.w - mu) * rstd * gw.w + gb.w;
  }
  __syncthreads();

  // proj: wave w handles quarter-range w of the K dim, lane = output dim d (0..63)
  const int d    = tid & 63;
  const int part = wave;
  const float* pwr = pw + (size_t)d * CS + part * 256;
  const float* snr = snf + part * 256;
  float acc = 0.f;
  #pragma unroll 4
  for (int kk = 0; kk < 32; ++kk) {
    float4 a0 = *(const float4*)(snr + kk * 8);
    float4 a1 = *(const float4*)(snr + kk * 8 + 4);
    float4 b0 = *(const float4*)(pwr + kk * 8);
    float4 b1 = *(const float4*)(pwr + kk * 8 + 4);
    acc += a0.x * b0.x + a0.y * b0.y + a0.z * b0.z + a0.w * b0.w
         + a1.x * b1.x + a1.y * b1.y + a1.z * b1.z + a1.w * b1.w;
  }
  pacc[part][d] = acc;
  __syncthreads();
  if (tid < 64) {
    float r = pacc[0][tid] + pacc[1][tid] + pacc[2][tid] + pacc[3][tid] + pb[tid];
    if (tid < 32) q_ws[row * 32 + tid] = f2bf(r);
    else          k_ws[row * 32 + (tid - 32)] = r;
  }
}

// ---------------- Kernel 2: out[i,j,z] = q[j,:] . W_i[z,:] + c_i[z] ----------------
// W_i[z,d] = k[i,d]*ow[z,d] + ow[z,32+d];  c_i[z] = ob[z] - sum_d k[i,d]*ow[z,32+d]
__global__ __launch_bounds__(256, 3) void pair_kernel(
    const unsigned short* __restrict__ q_ws,
    const float* __restrict__ k_ws,
    const float* __restrict__ ow,
    const float* __restrict__ ob,
    float* __restrict__ out) {
  const int bid  = blockIdx.x;
  const int i    = bid >> 2;     // k-row index
  const int jt   = bid & 3;      // 256-wide j tile
  const int tid  = threadIdx.x;
  const int lane = tid & 63;
  const int wave = tid >> 6;
  const int quad = lane >> 4;
  const int n16  = lane & 15;

  __shared__ __align__(16) unsigned short Wsh[CZ * 40];    // stride 40 pads banks
  __shared__ __align__(16) unsigned short Qsh[256 * 40];
  __shared__ float cvec[CZ];

  // ---- build W_i (bf16) and c_i (f32) ----
  {
    const int z  = tid >> 1;
    const int dh = (tid & 1) << 4;
    const float* kr  = k_ws + i * 32;
    const float* owr = ow + z * 64;
    #pragma unroll
    for (int t4 = 0; t4 < 4; ++t4) {
      const int d = dh + t4 * 4;
      float4 w1 = *(const float4*)(owr + d);
      float4 w2 = *(const float4*)(owr + 32 + d);
      Wsh[z * 40 + d + 0] = f2bf(kr[d + 0] * w1.x + w2.x);
      Wsh[z * 40 + d + 1] = f2bf(kr[d + 1] * w1.y + w2.y);
      Wsh[z * 40 + d + 2] = f2bf(kr[d + 2] * w1.z + w2.z);
      Wsh[z * 40 + d + 3] = f2bf(kr[d + 3] * w1.w + w2.w);
    }
    if ((tid & 1) == 0) {
      float c = ob[z];
      #pragma unroll
      for (int d = 0; d < 32; ++d) c -= kr[d] * owr[32 + d];
      cvec[z] = c;
    }
  }
  // ---- stage q tile (256 rows x 32 bf16), coalesced ----
  {
    const uint2* qsrc = (const uint2*)(q_ws + (size_t)jt * 256 * 32);
    #pragma unroll
    for (int it = 0; it < 8; ++it) {
      const int n2 = it * 256 + tid;   // uint2 index: 8 per row
      const int r  = n2 >> 3, dw = n2 & 7;
      uint2 vv = qsrc[n2];
      *(uint2*)((char*)Qsh + r * 80 + dw * 8) = vv;
    }
  }
  __syncthreads();

  // B-fragments: B[n=lane&15][k=quad*8+j] = W[z][d]
  short8 bfr[8];
  float  cv[8];
  #pragma unroll
  for (int c = 0; c < 8; ++c) {
    const int z = c * 16 + n16;
    bfr[c] = *(const short8*)&Wsh[z * 40 + quad * 8];
    cv[c]  = cvec[z];
  }

  const int jbase = jt * 256 + wave * 64;

  #pragma unroll
  for (int js = 0; js < 4; ++js) {
    // A-frag: A[m=lane&15][k=quad*8+j] = q[j_local][d]
    short8 afr = *(const short8*)&Qsh[(wave * 64 + js * 16 + n16) * 40 + quad * 8];
    // C/D: row(j) = quad*4+r, col(z) = c*16+n16
    float* orow = out + ((size_t)(i * 1024 + jbase + js * 16 + quad * 4)) * CZ + n16;
    #pragma unroll
    for (int c = 0; c < 8; ++c) {
      floatx4 acc = {cv[c], cv[c], cv[c], cv[c]};   // fold +c_i[z] into accumulator
      acc = __builtin_amdgcn_mfma_f32_16x16x32_bf16(afr, bfr[c], acc, 0, 0, 0);
      #pragma unroll
      for (int r = 0; r < 4; ++r) {
        orow[r * CZ + c * 16] = acc[r];   // 16 lanes x 4B = 64B segment, x4 quads
      }
    }
  }
}

extern "C" void kernel_launch(void* const* d_in, const int* in_sizes, int n_in,
                              void* d_out, int out_size, void* d_ws, size_t ws_size,
                              hipStream_t stream) {
  const float* seq = (const float*)d_in[0];
  const float* lnw = (const float*)d_in[1];
  const float* lnb = (const float*)d_in[2];
  const float* pw  = (const float*)d_in[3];
  const float* pb  = (const float*)d_in[4];
  const float* ow  = (const float*)d_in[5];
  const float* ob  = (const float*)d_in[6];
  float* out = (float*)d_out;

  unsigned short* q_ws = (unsigned short*)d_ws;                    // 1024*32 bf16 = 64 KB
  float*          k_ws = (float*)((char*)d_ws + 64 * 1024);        // 1024*32 f32 = 128 KB

  prep_kernel<<<1024, 256, 0, stream>>>(seq, lnw, lnb, pw, pb, q_ws, k_ws);
  pair_kernel<<<1024 * 4, 256, 0, stream>>>(q_ws, k_ws, ow, ob, out);
}